// Round 1
// baseline (4009.651 us; speedup 1.0000x reference)
//
#include <hip/hip_runtime.h>
#include <math.h>

#define NPTS 4096
#define DIM  64
#define MAX_ITERS 44

#define ALOG (-8.317766166719343f)   /* -log(4096) */
#define BLOG (-8.317766166719343f)

/* ---------------- min/max partial reduction (per-dim, both x and y) ------ */
__global__ void minmax_part_kernel(const float* __restrict__ x,
                                   const float* __restrict__ y,
                                   float* __restrict__ partmn,
                                   float* __restrict__ partmx) {
    int t = threadIdx.x;
    int bid = blockIdx.x;               // 128 blocks
    int g0 = bid * 256 + t;
    const int total = NPTS * DIM;       // 262144
    float mn = INFINITY, mx = -INFINITY;
    for (int g = g0; g < total; g += 128 * 256) {
        float v = x[g]; mn = fminf(mn, v); mx = fmaxf(mx, v);
        float w = y[g]; mn = fminf(mn, w); mx = fmaxf(mx, w);
    }
    __shared__ float smn[256], smx[256];
    smn[t] = mn; smx[t] = mx;
    __syncthreads();
    if (t < 64) {   // t == dim (strides are multiples of 64)
        for (int q = 1; q < 4; q++) {
            mn = fminf(mn, smn[t + 64 * q]);
            mx = fmaxf(mx, smx[t + 64 * q]);
        }
        partmn[bid * 64 + t] = mn;
        partmx[bid * 64 + t] = mx;
    }
}

/* ---------------- eps schedule (replicates numpy in f64) ----------------- */
__global__ void schedule_kernel(const float* __restrict__ partmn,
                                const float* __restrict__ partmx,
                                int* __restrict__ hdr,
                                float* __restrict__ sched) {
    int d = threadIdx.x;  // 64 threads
    float mn = INFINITY, mx = -INFINITY;
    for (int b = 0; b < 128; b++) {
        mn = fminf(mn, partmn[b * 64 + d]);
        mx = fmaxf(mx, partmx[b * 64 + d]);
    }
    float range = mx - mn;              // f32, like numpy
    __shared__ float r2[64];
    r2[d] = range * range;
    __syncthreads();
    if (d == 0) {
        float ss = 0.f;
        for (int k = 0; k < 64; k++) ss += r2[k];
        float diam_f = sqrtf(ss);       // np.linalg.norm on f32 -> f32
        double diam = (double)diam_f;
        double start = 2.0 * log(diam);
        double stop  = 2.0 * log(0.05);
        double step  = 2.0 * log(0.8);
        int n_ar = (int)ceil((stop - start) / step);
        if (n_ar < 0) n_ar = 0;
        int n_eps = n_ar + 2;
        if (n_eps > 64) n_eps = 64;
        sched[0] = (float)(diam * diam);
        for (int k = 0; k < n_ar && (1 + k) < 63; k++)
            sched[1 + k] = (float)exp(start + step * (double)k);
        sched[n_eps - 1] = 0.0025f;     /* BLUR**P */
        for (int k = n_eps; k < 64; k++) sched[k] = 0.0025f;
        hdr[0] = n_eps;
    }
}

/* ---------------- squared norms (wave per row) --------------------------- */
__global__ void sqnorm_kernel(const float* __restrict__ X, float* __restrict__ out) {
    int wave = (blockIdx.x * blockDim.x + threadIdx.x) >> 6;
    int lane = threadIdx.x & 63;
    if (wave >= NPTS) return;
    float v = X[wave * DIM + lane];
    float s = v * v;
    for (int o = 32; o > 0; o >>= 1) s += __shfl_xor(s, o, 64);
    if (lane == 0) out[wave] = s;
}

/* ---------------- Gram: G[i][j] = dot(A_i, B_j), 64x64 tile per block ---- */
__global__ __launch_bounds__(256) void gram_kernel(const float* __restrict__ A,
                                                   const float* __restrict__ B,
                                                   float* __restrict__ G) {
    __shared__ float As[64][68], Bs[64][68];
    int t = threadIdx.x;
    int i0 = blockIdx.y * 64, j0 = blockIdx.x * 64;
    for (int q = 0; q < 4; q++) {
        int fi = q * 256 + t;
        int r = fi >> 4, c4 = (fi & 15) * 4;
        *(float4*)&As[r][c4] = *(const float4*)&A[(i0 + r) * DIM + c4];
        *(float4*)&Bs[r][c4] = *(const float4*)&B[(j0 + r) * DIM + c4];
    }
    __syncthreads();
    int tx = t & 15, ty = t >> 4;
    float acc[4][4] = {};
    for (int k = 0; k < 64; k++) {
        float a[4], b[4];
#pragma unroll
        for (int u = 0; u < 4; u++) a[u] = As[ty + 16 * u][k];
#pragma unroll
        for (int v = 0; v < 4; v++) b[v] = Bs[tx + 16 * v][k];
#pragma unroll
        for (int u = 0; u < 4; u++)
#pragma unroll
            for (int v = 0; v < 4; v++) acc[u][v] = fmaf(a[u], b[v], acc[u][v]);
    }
    for (int u = 0; u < 4; u++)
        for (int v = 0; v < 4; v++)
            G[(size_t)(i0 + ty + 16 * u) * NPTS + j0 + tx + 16 * v] = acc[u][v];
}

/* ---------------- softmin over rows of G (wave per row, 2-pass LSE) ------ */
/* out_i = 0.5*rowsq_i - eps * LSE_j( baselog + (fprev_j - 0.5*colsq_j + G_ij)/eps ) */
__global__ __launch_bounds__(256) void softmin_rows_kernel(
        const float* __restrict__ G, const float* __restrict__ rowsq,
        const float* __restrict__ colsq, const float* __restrict__ fprev,
        const float* __restrict__ fold, float* __restrict__ fout,
        float baselog, const int* __restrict__ hdr, const float* __restrict__ sched,
        int t, int mode) {
    int gw = (blockIdx.x * 256 + threadIdx.x) >> 6;
    int lane = threadIdx.x & 63;
    if (gw >= NPTS) return;
    int n_eps = hdr[0];
    if (mode != 0 && t >= n_eps) {           // inactive padded iteration: copy
        if (lane == 0) fout[gw] = fold[gw];
        return;
    }
    int idx = (t < 0) ? (n_eps - 1) : t;
    float eps = sched[idx];
    float inv = 1.0f / eps;
    const float* Gr = G + (size_t)gw * NPTS;

    float m = -INFINITY;
    for (int c = lane * 4; c < NPTS; c += 256) {
        float4 g4 = *(const float4*)(Gr + c);
        float4 cs = *(const float4*)(colsq + c);
        float4 fp = fprev ? *(const float4*)(fprev + c) : make_float4(0.f, 0.f, 0.f, 0.f);
        float v0 = fmaf(fp.x - 0.5f * cs.x + g4.x, inv, baselog);
        float v1 = fmaf(fp.y - 0.5f * cs.y + g4.y, inv, baselog);
        float v2 = fmaf(fp.z - 0.5f * cs.z + g4.z, inv, baselog);
        float v3 = fmaf(fp.w - 0.5f * cs.w + g4.w, inv, baselog);
        m = fmaxf(m, fmaxf(fmaxf(v0, v1), fmaxf(v2, v3)));
    }
    for (int o = 32; o > 0; o >>= 1) m = fmaxf(m, __shfl_xor(m, o, 64));

    float s = 0.f;
    for (int c = lane * 4; c < NPTS; c += 256) {
        float4 g4 = *(const float4*)(Gr + c);
        float4 cs = *(const float4*)(colsq + c);
        float4 fp = fprev ? *(const float4*)(fprev + c) : make_float4(0.f, 0.f, 0.f, 0.f);
        float v0 = fmaf(fp.x - 0.5f * cs.x + g4.x, inv, baselog);
        float v1 = fmaf(fp.y - 0.5f * cs.y + g4.y, inv, baselog);
        float v2 = fmaf(fp.z - 0.5f * cs.z + g4.z, inv, baselog);
        float v3 = fmaf(fp.w - 0.5f * cs.w + g4.w, inv, baselog);
        s += expf(v0 - m) + expf(v1 - m) + expf(v2 - m) + expf(v3 - m);
    }
    for (int o = 32; o > 0; o >>= 1) s += __shfl_xor(s, o, 64);

    if (lane == 0) {
        float res = 0.5f * rowsq[gw] - eps * (m + logf(s));
        fout[gw] = (mode == 1) ? 0.5f * (fold[gw] + res) : res;
    }
}

/* ---------------- softmin over COLUMNS of G (transposed read), stage 1 --- */
/* grid (64 colgroups, 4 j-chunks); partial (m,s) per (chunk, column).      */
__global__ __launch_bounds__(256) void softmin_colsT_part_kernel(
        const float* __restrict__ G, const float* __restrict__ colsq /* x2 */,
        const float* __restrict__ fprev, float baselog,
        const int* __restrict__ hdr, const float* __restrict__ sched,
        int t, int mode,
        float* __restrict__ partM, float* __restrict__ partS) {
    int n_eps = hdr[0];
    if (mode != 0 && t >= n_eps) return;     // stage 2 does the copy
    int idx = (t < 0) ? (n_eps - 1) : t;
    float eps = sched[idx];
    float inv = 1.0f / eps;

    __shared__ float tile[64][68];
    int tt = threadIdx.x;
    int c = tt & 63, rq = tt >> 6;
    int i0 = blockIdx.x * 64;    // columns i0..i0+63
    int jc = blockIdx.y;         // j chunk: rows jc*1024 .. +1023

    float m = -INFINITY, s = 0.f;
    for (int jt = 0; jt < 16; jt++) {
        int j0 = jc * 1024 + jt * 64;
        __syncthreads();
        for (int q = 0; q < 4; q++) {
            int fi = q * 256 + tt;
            int r = fi >> 4, c4 = (fi & 15) * 4;
            *(float4*)&tile[r][c4] = *(const float4*)&G[(size_t)(j0 + r) * NPTS + i0 + c4];
        }
        __syncthreads();
        float v[16];
        float lm = -INFINITY;
#pragma unroll
        for (int k = 0; k < 16; k++) {
            int j = j0 + rq * 16 + k;
            float wv = (fprev ? fprev[j] : 0.f) - 0.5f * colsq[j];  // wave-uniform
            v[k] = fmaf(wv + tile[rq * 16 + k][c], inv, baselog);
            lm = fmaxf(lm, v[k]);
        }
        if (lm > m) { s *= expf(m - lm); m = lm; }
#pragma unroll
        for (int k = 0; k < 16; k++) s += expf(v[k] - m);
    }
    __shared__ float sm[4][64], ssum[4][64];
    sm[rq][c] = m; ssum[rq][c] = s;
    __syncthreads();
    if (tt < 64) {
        float M = -INFINITY;
        for (int q = 0; q < 4; q++) M = fmaxf(M, sm[q][tt]);
        float S = 0.f;
        for (int q = 0; q < 4; q++) S += ssum[q][tt] * expf(sm[q][tt] - M);
        partM[jc * NPTS + i0 + tt] = M;
        partS[jc * NPTS + i0 + tt] = S;
    }
}

/* ---------------- columns softmin, stage 2: combine 4 partials ----------- */
__global__ void softmin_colsT_comb_kernel(
        const float* __restrict__ partM, const float* __restrict__ partS,
        const float* __restrict__ rowsq /* y2 */,
        const float* __restrict__ fold, float* __restrict__ fout,
        const int* __restrict__ hdr, const float* __restrict__ sched,
        int t, int mode) {
    int i = blockIdx.x * 256 + threadIdx.x;
    if (i >= NPTS) return;
    int n_eps = hdr[0];
    if (mode != 0 && t >= n_eps) { fout[i] = fold[i]; return; }
    int idx = (t < 0) ? (n_eps - 1) : t;
    float eps = sched[idx];
    float M = -INFINITY;
    for (int q = 0; q < 4; q++) M = fmaxf(M, partM[q * NPTS + i]);
    float S = 0.f;
    for (int q = 0; q < 4; q++) S += partS[q * NPTS + i] * expf(partM[q * NPTS + i] - M);
    float res = 0.5f * rowsq[i] - eps * (M + logf(S));
    fout[i] = (mode == 1) ? 0.5f * (fold[i] + res) : res;
}

/* ---------------- final reduction: mean(fba-faa)+mean(gab-gbb) ----------- */
__global__ void reduce_kernel(const float* __restrict__ fba, const float* __restrict__ faa,
                              const float* __restrict__ gab, const float* __restrict__ gbb,
                              float* __restrict__ out) {
    int t = threadIdx.x;
    double s1 = 0.0, s2 = 0.0;
    for (int i = t; i < NPTS; i += 256) {
        s1 += (double)fba[i] - (double)faa[i];
        s2 += (double)gab[i] - (double)gbb[i];
    }
    __shared__ double sh1[256], sh2[256];
    sh1[t] = s1; sh2[t] = s2;
    __syncthreads();
    for (int o = 128; o > 0; o >>= 1) {
        if (t < o) { sh1[t] += sh1[t + o]; sh2[t] += sh2[t + o]; }
        __syncthreads();
    }
    if (t == 0) out[0] = (float)(sh1[0] / NPTS + sh2[0] / NPTS);
}

extern "C" void kernel_launch(void* const* d_in, const int* in_sizes, int n_in,
                              void* d_out, int out_size, void* d_ws, size_t ws_size,
                              hipStream_t stream) {
    const float* x = (const float*)d_in[0];
    const float* y = (const float*)d_in[1];
    float* out = (float*)d_out;
    float* w = (float*)d_ws;

    /* workspace layout (float offsets) */
    int*   hdr   = (int*)w;            /* 16 */
    float* sched = w + 16;             /* 64 */
    float* pmn   = w + 80;             /* 8192 */
    float* pmx   = w + 80 + 8192;      /* 8192 */
    float* x2    = w + 80 + 16384;     /* 4096 */
    float* y2    = x2 + 4096;          /* 4096 */
    float* st    = y2 + 4096;          /* 8*4096 state (ping-pong) */
    float* fba[2] = { st,             st + 4096 };
    float* gab[2] = { st + 2 * 4096,  st + 3 * 4096 };
    float* faa[2] = { st + 4 * 4096,  st + 5 * 4096 };
    float* gbb[2] = { st + 6 * 4096,  st + 7 * 4096 };
    float* partM = st + 8 * 4096;      /* 4*4096 */
    float* partS = partM + 4 * 4096;   /* 4*4096 */
    const size_t NN = (size_t)NPTS * NPTS;
    float* Gxy = w + 98304;
    float* Gxx = Gxy + NN;
    float* Gyy = Gxx + NN;

    /* setup */
    hipLaunchKernelGGL(minmax_part_kernel, dim3(128), dim3(256), 0, stream, x, y, pmn, pmx);
    hipLaunchKernelGGL(schedule_kernel, dim3(1), dim3(64), 0, stream, pmn, pmx, hdr, sched);
    hipLaunchKernelGGL(sqnorm_kernel, dim3(1024), dim3(256), 0, stream, x, x2);
    hipLaunchKernelGGL(sqnorm_kernel, dim3(1024), dim3(256), 0, stream, y, y2);
    hipLaunchKernelGGL(gram_kernel, dim3(64, 64), dim3(256), 0, stream, x, y, Gxy);
    hipLaunchKernelGGL(gram_kernel, dim3(64, 64), dim3(256), 0, stream, x, x, Gxx);
    hipLaunchKernelGGL(gram_kernel, dim3(64, 64), dim3(256), 0, stream, y, y, Gyy);

    /* init potentials at eps_list[0] (mode 0, fprev = null) */
    hipLaunchKernelGGL(softmin_rows_kernel, dim3(1024), dim3(256), 0, stream,
                       Gxy, x2, y2, (const float*)nullptr, (const float*)nullptr, fba[0],
                       BLOG, hdr, sched, 0, 0);
    hipLaunchKernelGGL(softmin_colsT_part_kernel, dim3(64, 4), dim3(256), 0, stream,
                       Gxy, x2, (const float*)nullptr, ALOG, hdr, sched, 0, 0, partM, partS);
    hipLaunchKernelGGL(softmin_colsT_comb_kernel, dim3(16), dim3(256), 0, stream,
                       partM, partS, y2, (const float*)nullptr, gab[0], hdr, sched, 0, 0);
    hipLaunchKernelGGL(softmin_rows_kernel, dim3(1024), dim3(256), 0, stream,
                       Gxx, x2, x2, (const float*)nullptr, (const float*)nullptr, faa[0],
                       ALOG, hdr, sched, 0, 0);
    hipLaunchKernelGGL(softmin_rows_kernel, dim3(1024), dim3(256), 0, stream,
                       Gyy, y2, y2, (const float*)nullptr, (const float*)nullptr, gbb[0],
                       BLOG, hdr, sched, 0, 0);

    /* annealing loop (fixed MAX_ITERS launches; t >= n_eps degrade to copy) */
    int cur = 0;
    for (int t = 0; t < MAX_ITERS; t++) {
        int nx = cur ^ 1;
        hipLaunchKernelGGL(softmin_rows_kernel, dim3(1024), dim3(256), 0, stream,
                           Gxy, x2, y2, gab[cur], fba[cur], fba[nx], BLOG, hdr, sched, t, 1);
        hipLaunchKernelGGL(softmin_colsT_part_kernel, dim3(64, 4), dim3(256), 0, stream,
                           Gxy, x2, fba[cur], ALOG, hdr, sched, t, 1, partM, partS);
        hipLaunchKernelGGL(softmin_colsT_comb_kernel, dim3(16), dim3(256), 0, stream,
                           partM, partS, y2, gab[cur], gab[nx], hdr, sched, t, 1);
        hipLaunchKernelGGL(softmin_rows_kernel, dim3(1024), dim3(256), 0, stream,
                           Gxx, x2, x2, faa[cur], faa[cur], faa[nx], ALOG, hdr, sched, t, 1);
        hipLaunchKernelGGL(softmin_rows_kernel, dim3(1024), dim3(256), 0, stream,
                           Gyy, y2, y2, gbb[cur], gbb[cur], gbb[nx], BLOG, hdr, sched, t, 1);
        cur = nx;
    }

    /* final extrapolation at eps_final (t=-1 -> last eps, mode 0) */
    int nx = cur ^ 1;
    hipLaunchKernelGGL(softmin_rows_kernel, dim3(1024), dim3(256), 0, stream,
                       Gxy, x2, y2, gab[cur], (const float*)nullptr, fba[nx], BLOG, hdr, sched, -1, 0);
    hipLaunchKernelGGL(softmin_colsT_part_kernel, dim3(64, 4), dim3(256), 0, stream,
                       Gxy, x2, fba[cur], ALOG, hdr, sched, -1, 0, partM, partS);
    hipLaunchKernelGGL(softmin_colsT_comb_kernel, dim3(16), dim3(256), 0, stream,
                       partM, partS, y2, (const float*)nullptr, gab[nx], hdr, sched, -1, 0);
    hipLaunchKernelGGL(softmin_rows_kernel, dim3(1024), dim3(256), 0, stream,
                       Gxx, x2, x2, faa[cur], (const float*)nullptr, faa[nx], ALOG, hdr, sched, -1, 0);
    hipLaunchKernelGGL(softmin_rows_kernel, dim3(1024), dim3(256), 0, stream,
                       Gyy, y2, y2, gbb[cur], (const float*)nullptr, gbb[nx], BLOG, hdr, sched, -1, 0);

    hipLaunchKernelGGL(reduce_kernel, dim3(1), dim3(256), 0, stream,
                       fba[nx], faa[nx], gab[nx], gbb[nx], out);
}

// Round 2
// 1292.464 us; speedup vs baseline: 3.1023x; 3.1023x over previous
//
#include <hip/hip_runtime.h>
#include <math.h>

#define NPTS 4096
#define DIM  64
#define MAX_ITERS 44
#define NCHUNK 32           /* 4096 / 128 */
#define TILE 128

#define ALOG (-8.317766166719343f)   /* -log(4096) */
#define BLOG (-8.317766166719343f)
#define L2E  (1.4426950408889634f)
#define LN2  (0.6931471805599453f)

#if __has_builtin(__builtin_amdgcn_exp2f)
#define EXP2F(x) __builtin_amdgcn_exp2f(x)
#else
#define EXP2F(x) exp2f(x)
#endif
#if __has_builtin(__builtin_amdgcn_logf)
#define LOG2F(x) __builtin_amdgcn_logf(x)
#else
#define LOG2F(x) log2f(x)
#endif

/* ---------------- min/max partial reduction (per-dim, both x and y) ------ */
__global__ void minmax_part_kernel(const float* __restrict__ x,
                                   const float* __restrict__ y,
                                   float* __restrict__ partmn,
                                   float* __restrict__ partmx) {
    int t = threadIdx.x;
    int bid = blockIdx.x;               // 128 blocks
    int g0 = bid * 256 + t;
    const int total = NPTS * DIM;
    float mn = INFINITY, mx = -INFINITY;
    for (int g = g0; g < total; g += 128 * 256) {
        float v = x[g]; mn = fminf(mn, v); mx = fmaxf(mx, v);
        float w = y[g]; mn = fminf(mn, w); mx = fmaxf(mx, w);
    }
    __shared__ float smn[256], smx[256];
    smn[t] = mn; smx[t] = mx;
    __syncthreads();
    if (t < 64) {
        for (int q = 1; q < 4; q++) {
            mn = fminf(mn, smn[t + 64 * q]);
            mx = fmaxf(mx, smx[t + 64 * q]);
        }
        partmn[bid * 64 + t] = mn;
        partmx[bid * 64 + t] = mx;
    }
}

/* ---------------- eps schedule (replicates numpy in f64) ----------------- */
__global__ void schedule_kernel(const float* __restrict__ partmn,
                                const float* __restrict__ partmx,
                                int* __restrict__ hdr,
                                float* __restrict__ sched) {
    int d = threadIdx.x;  // 64 threads
    float mn = INFINITY, mx = -INFINITY;
    for (int b = 0; b < 128; b++) {
        mn = fminf(mn, partmn[b * 64 + d]);
        mx = fmaxf(mx, partmx[b * 64 + d]);
    }
    float range = mx - mn;
    __shared__ float r2[64];
    r2[d] = range * range;
    __syncthreads();
    if (d == 0) {
        float ss = 0.f;
        for (int k = 0; k < 64; k++) ss += r2[k];
        float diam_f = sqrtf(ss);
        double diam = (double)diam_f;
        double start = 2.0 * log(diam);
        double stop  = 2.0 * log(0.05);
        double step  = 2.0 * log(0.8);
        int n_ar = (int)ceil((stop - start) / step);
        if (n_ar < 0) n_ar = 0;
        int n_eps = n_ar + 2;
        if (n_eps > 64) n_eps = 64;
        sched[0] = (float)(diam * diam);
        for (int k = 0; k < n_ar && (1 + k) < 63; k++)
            sched[1 + k] = (float)exp(start + step * (double)k);
        sched[n_eps - 1] = 0.0025f;
        for (int k = n_eps; k < 64; k++) sched[k] = 0.0025f;
        hdr[0] = n_eps;
    }
}

/* ---------------- squared norms (wave per row) --------------------------- */
__global__ void sqnorm_kernel(const float* __restrict__ X, float* __restrict__ out) {
    int wave = (blockIdx.x * blockDim.x + threadIdx.x) >> 6;
    int lane = threadIdx.x & 63;
    if (wave >= NPTS) return;
    float v = X[wave * DIM + lane];
    float s = v * v;
    for (int o = 32; o > 0; o >>= 1) s += __shfl_xor(s, o, 64);
    if (lane == 0) out[wave] = s;
}

/* ---------------- Gram: G[i][j] = dot(A_i, B_j), 64x64 tile per block ---- */
__global__ __launch_bounds__(256) void gram_kernel(const float* __restrict__ A,
                                                   const float* __restrict__ B,
                                                   float* __restrict__ G) {
    __shared__ float As[64][68], Bs[64][68];
    int t = threadIdx.x;
    int i0 = blockIdx.y * 64, j0 = blockIdx.x * 64;
    for (int q = 0; q < 4; q++) {
        int fi = q * 256 + t;
        int r = fi >> 4, c4 = (fi & 15) * 4;
        *(float4*)&As[r][c4] = *(const float4*)&A[(i0 + r) * DIM + c4];
        *(float4*)&Bs[r][c4] = *(const float4*)&B[(j0 + r) * DIM + c4];
    }
    __syncthreads();
    int tx = t & 15, ty = t >> 4;
    float acc[4][4] = {};
    for (int k = 0; k < 64; k++) {
        float a[4], b[4];
#pragma unroll
        for (int u = 0; u < 4; u++) a[u] = As[ty + 16 * u][k];
#pragma unroll
        for (int v = 0; v < 4; v++) b[v] = Bs[tx + 16 * v][k];
#pragma unroll
        for (int u = 0; u < 4; u++)
#pragma unroll
            for (int v = 0; v < 4; v++) acc[u][v] = fmaf(a[u], b[v], acc[u][v]);
    }
    for (int u = 0; u < 4; u++)
        for (int v = 0; v < 4; v++)
            G[(size_t)(i0 + ty + 16 * u) * NPTS + j0 + tx + 16 * v] = acc[u][v];
}

/* ---------------- fused tile pass: all 3 matrices, both directions ------- */
/* v2_ij = h2[j] + G_ij*inv2 (log2 domain). Row-dir LSE -> partial for rows,
   col-dir LSE -> partial for cols. Gxy tiles: 1024 (b<1024).  Gxx/Gyy:
   upper-triangle tiles only; col-dir covers the mirrored half.            */
struct TileArgs {
    const float *Gxy, *Gxx, *Gyy;
    const float *x2, *y2;
    const float *fba, *gab, *faa, *gbb;      /* prev potentials (null=init) */
    float *PxyR_m, *PxyR_s, *PxyC_m, *PxyC_s;
    float *Pxx_m, *Pxx_s, *Pyy_m, *Pyy_s;
    const int* hdr; const float* sched;
    int t; int mode;                          /* mode1=anneal iter, mode0=init/final */
};

__global__ __launch_bounds__(256) void tile_kernel(TileArgs A) {
    int n_eps = A.hdr[0];
    if (A.mode == 1 && A.t >= n_eps) return;  /* padded iteration */
    int idx = (A.t < 0) ? (n_eps - 1) : A.t;
    float eps = A.sched[idx];
    float inv2 = (1.0f / eps) * L2E;

    int b = blockIdx.x;
    const float *G, *hc_f, *hc_sq, *hr_f, *hr_sq;
    float *Prm, *Prs, *Pcm, *Pcs;
    int ti, tj; bool diag = false;
    if (b < 1024) {
        ti = b >> 5; tj = b & 31;
        G = A.Gxy;
        hc_f = A.gab; hc_sq = A.y2;      /* row-dir h over columns j (y side) */
        hr_f = A.fba; hr_sq = A.x2;      /* col-dir h over rows i (x side)    */
        Prm = A.PxyR_m; Prs = A.PxyR_s; Pcm = A.PxyC_m; Pcs = A.PxyC_s;
    } else {
        int u;
        if (b < 1024 + 528) {
            u = b - 1024; G = A.Gxx; hc_f = A.faa; hc_sq = A.x2;
            Prm = A.Pxx_m; Prs = A.Pxx_s; Pcm = A.Pxx_m; Pcs = A.Pxx_s;
        } else {
            u = b - 1552; G = A.Gyy; hc_f = A.gbb; hc_sq = A.y2;
            Prm = A.Pyy_m; Prs = A.Pyy_s; Pcm = A.Pyy_m; Pcs = A.Pyy_s;
        }
        hr_f = hc_f; hr_sq = hc_sq;
        ti = 0; while (u >= NCHUNK - ti) { u -= NCHUNK - ti; ti++; }
        tj = ti + u;
        diag = (ti == tj);
    }
    /* ALOG == BLOG numerically; base is uniform */
    const float base2 = ALOG * L2E;

    __shared__ float tile[64][65];
    __shared__ float h2c[128], h2r[128];
    __shared__ float red_m[4][64], red_s[4][64];

    int tt = threadIdx.x;
    int gi0 = ti * TILE, gj0 = tj * TILE;
    if (tt < 128) {
        int j = gj0 + tt;
        float f = hc_f ? hc_f[j] : 0.f;
        h2c[tt] = base2 + (f - 0.5f * hc_sq[j]) * inv2;
    } else {
        int i = gi0 + (tt - 128);
        float f = hr_f ? hr_f[i] : 0.f;
        h2r[tt - 128] = base2 + (f - 0.5f * hr_sq[i]) * inv2;
    }

    float rm[2] = {-INFINITY, -INFINITY}, rs[2] = {0.f, 0.f};
    float cm[2] = {-INFINITY, -INFINITY}, cs[2] = {0.f, 0.f};
    int lr = tt & 63, lq = tt >> 6;

    for (int qc = 0; qc < 2; qc++) {
        for (int qr = 0; qr < 2; qr++) {
            __syncthreads();
            {   /* stage 64x64 quadrant */
                const float* src = G + (size_t)(gi0 + qr * 64) * NPTS + gj0 + qc * 64;
                for (int q = 0; q < 4; q++) {
                    int fi = q * 256 + tt;
                    int r = fi >> 4, c4 = (fi & 15) * 4;
                    float4 v4 = *(const float4*)(src + (size_t)r * NPTS + c4);
                    tile[r][c4 + 0] = v4.x; tile[r][c4 + 1] = v4.y;
                    tile[r][c4 + 2] = v4.z; tile[r][c4 + 3] = v4.w;
                }
            }
            __syncthreads();
            {   /* row-dir: thread owns row lr (slab qr), col quarter lq */
                float v[16], lm = -INFINITY;
#pragma unroll
                for (int k = 0; k < 16; k++) {
                    v[k] = fmaf(tile[lr][lq * 16 + k], inv2, h2c[qc * 64 + lq * 16 + k]);
                    lm = fmaxf(lm, v[k]);
                }
                float nm = fmaxf(rm[qr], lm);
                float acc = rs[qr] * EXP2F(rm[qr] - nm);
#pragma unroll
                for (int k = 0; k < 16; k++) acc += EXP2F(v[k] - nm);
                rm[qr] = nm; rs[qr] = acc;
            }
            if (!diag) {   /* col-dir: thread owns col lr (slab qc), row quarter lq */
                float v[16], lm = -INFINITY;
#pragma unroll
                for (int k = 0; k < 16; k++) {
                    v[k] = fmaf(tile[lq * 16 + k][lr], inv2, h2r[qr * 64 + lq * 16 + k]);
                    lm = fmaxf(lm, v[k]);
                }
                float nm = fmaxf(cm[qc], lm);
                float acc = cs[qc] * EXP2F(cm[qc] - nm);
#pragma unroll
                for (int k = 0; k < 16; k++) acc += EXP2F(v[k] - nm);
                cm[qc] = nm; cs[qc] = acc;
            }
        }
    }

    /* flush row partials: P[tj][gi] */
    for (int qr = 0; qr < 2; qr++) {
        __syncthreads();
        red_m[lq][lr] = rm[qr]; red_s[lq][lr] = rs[qr];
        __syncthreads();
        if (tt < 64) {
            float M = fmaxf(fmaxf(red_m[0][tt], red_m[1][tt]),
                            fmaxf(red_m[2][tt], red_m[3][tt]));
            float S = red_s[0][tt] * EXP2F(red_m[0][tt] - M)
                    + red_s[1][tt] * EXP2F(red_m[1][tt] - M)
                    + red_s[2][tt] * EXP2F(red_m[2][tt] - M)
                    + red_s[3][tt] * EXP2F(red_m[3][tt] - M);
            int gi = gi0 + qr * 64 + tt;
            Prm[tj * NPTS + gi] = M; Prs[tj * NPTS + gi] = S;
        }
    }
    /* flush col partials: P[ti][gj] */
    if (!diag) {
        for (int qc = 0; qc < 2; qc++) {
            __syncthreads();
            red_m[lq][lr] = cm[qc]; red_s[lq][lr] = cs[qc];
            __syncthreads();
            if (tt < 64) {
                float M = fmaxf(fmaxf(red_m[0][tt], red_m[1][tt]),
                                fmaxf(red_m[2][tt], red_m[3][tt]));
                float S = red_s[0][tt] * EXP2F(red_m[0][tt] - M)
                        + red_s[1][tt] * EXP2F(red_m[1][tt] - M)
                        + red_s[2][tt] * EXP2F(red_m[2][tt] - M)
                        + red_s[3][tt] * EXP2F(red_m[3][tt] - M);
                int gj = gj0 + qc * 64 + tt;
                Pcm[ti * NPTS + gj] = M; Pcs[ti * NPTS + gj] = S;
            }
        }
    }
}

/* ---------------- combine: merge 32 chunk partials per output row -------- */
struct CombArgs {
    const float *PxyR_m, *PxyR_s, *PxyC_m, *PxyC_s;
    const float *Pxx_m, *Pxx_s, *Pyy_m, *Pyy_s;
    const float *x2, *y2;
    const float *fba_old, *gab_old, *faa_old, *gbb_old;
    float *fba, *gab, *faa, *gbb;
    const int* hdr; const float* sched; int t; int mode;
};

__global__ void comb_kernel(CombArgs A) {
    int vec = blockIdx.x >> 4;                       /* 16 blocks per vector */
    int r = (blockIdx.x & 15) * 256 + threadIdx.x;
    int n_eps = A.hdr[0];
    const float *Pm, *Ps, *sq, *old; float *out;
    switch (vec) {
        case 0:  Pm = A.PxyR_m; Ps = A.PxyR_s; sq = A.x2; old = A.fba_old; out = A.fba; break;
        case 1:  Pm = A.PxyC_m; Ps = A.PxyC_s; sq = A.y2; old = A.gab_old; out = A.gab; break;
        case 2:  Pm = A.Pxx_m;  Ps = A.Pxx_s;  sq = A.x2; old = A.faa_old; out = A.faa; break;
        default: Pm = A.Pyy_m;  Ps = A.Pyy_s;  sq = A.y2; old = A.gbb_old; out = A.gbb; break;
    }
    if (A.mode == 1 && A.t >= n_eps) { out[r] = old[r]; return; }
    int idx = (A.t < 0) ? (n_eps - 1) : A.t;
    float eps = A.sched[idx];
    float M = -INFINITY;
    for (int q = 0; q < NCHUNK; q++) M = fmaxf(M, Pm[q * NPTS + r]);
    float S = 0.f;
    for (int q = 0; q < NCHUNK; q++) S += Ps[q * NPTS + r] * EXP2F(Pm[q * NPTS + r] - M);
    float res = 0.5f * sq[r] - eps * LN2 * (M + LOG2F(S));
    out[r] = (A.mode == 1) ? 0.5f * (old[r] + res) : res;
}

/* ---------------- final reduction: mean(fba-faa)+mean(gab-gbb) ----------- */
__global__ void reduce_kernel(const float* __restrict__ fba, const float* __restrict__ faa,
                              const float* __restrict__ gab, const float* __restrict__ gbb,
                              float* __restrict__ out) {
    int t = threadIdx.x;
    double s1 = 0.0, s2 = 0.0;
    for (int i = t; i < NPTS; i += 256) {
        s1 += (double)fba[i] - (double)faa[i];
        s2 += (double)gab[i] - (double)gbb[i];
    }
    __shared__ double sh1[256], sh2[256];
    sh1[t] = s1; sh2[t] = s2;
    __syncthreads();
    for (int o = 128; o > 0; o >>= 1) {
        if (t < o) { sh1[t] += sh1[t + o]; sh2[t] += sh2[t + o]; }
        __syncthreads();
    }
    if (t == 0) out[0] = (float)(sh1[0] / NPTS + sh2[0] / NPTS);
}

extern "C" void kernel_launch(void* const* d_in, const int* in_sizes, int n_in,
                              void* d_out, int out_size, void* d_ws, size_t ws_size,
                              hipStream_t stream) {
    const float* x = (const float*)d_in[0];
    const float* y = (const float*)d_in[1];
    float* out = (float*)d_out;
    float* w = (float*)d_ws;

    int*   hdr   = (int*)w;                /* 16 */
    float* sched = w + 16;                 /* 64 */
    float* pmn   = w + 80;                 /* 8192 */
    float* pmx   = w + 8272;               /* 8192 */
    float* x2    = w + 16464;              /* 4096 */
    float* y2    = w + 20560;              /* 4096 */
    float* st    = w + 24656;              /* 8*4096 ping-pong state */
    float* fba[2] = { st,            st + 4096 };
    float* gab[2] = { st + 2*4096,   st + 3*4096 };
    float* faa[2] = { st + 4*4096,   st + 5*4096 };
    float* gbb[2] = { st + 6*4096,   st + 7*4096 };
    float* P = w + 57424;                  /* 8 x 131072 partials */
    float* PxyR_m = P;             float* PxyR_s = P + 131072;
    float* PxyC_m = P + 2*131072;  float* PxyC_s = P + 3*131072;
    float* Pxx_m  = P + 4*131072;  float* Pxx_s  = P + 5*131072;
    float* Pyy_m  = P + 6*131072;  float* Pyy_s  = P + 7*131072;
    const size_t NN = (size_t)NPTS * NPTS;
    float* Gxy = w + 2097152;
    float* Gxx = Gxy + NN;
    float* Gyy = Gxx + NN;

    /* setup */
    hipLaunchKernelGGL(minmax_part_kernel, dim3(128), dim3(256), 0, stream, x, y, pmn, pmx);
    hipLaunchKernelGGL(schedule_kernel, dim3(1), dim3(64), 0, stream, pmn, pmx, hdr, sched);
    hipLaunchKernelGGL(sqnorm_kernel, dim3(1024), dim3(256), 0, stream, x, x2);
    hipLaunchKernelGGL(sqnorm_kernel, dim3(1024), dim3(256), 0, stream, y, y2);
    hipLaunchKernelGGL(gram_kernel, dim3(64, 64), dim3(256), 0, stream, x, y, Gxy);
    hipLaunchKernelGGL(gram_kernel, dim3(64, 64), dim3(256), 0, stream, x, x, Gxx);
    hipLaunchKernelGGL(gram_kernel, dim3(64, 64), dim3(256), 0, stream, y, y, Gyy);

    const int NBLK = 1024 + 528 + 528;     /* 2080 */
    TileArgs TA;
    TA.Gxy = Gxy; TA.Gxx = Gxx; TA.Gyy = Gyy;
    TA.x2 = x2; TA.y2 = y2;
    TA.PxyR_m = PxyR_m; TA.PxyR_s = PxyR_s; TA.PxyC_m = PxyC_m; TA.PxyC_s = PxyC_s;
    TA.Pxx_m = Pxx_m; TA.Pxx_s = Pxx_s; TA.Pyy_m = Pyy_m; TA.Pyy_s = Pyy_s;
    TA.hdr = hdr; TA.sched = sched;

    CombArgs CA;
    CA.PxyR_m = PxyR_m; CA.PxyR_s = PxyR_s; CA.PxyC_m = PxyC_m; CA.PxyC_s = PxyC_s;
    CA.Pxx_m = Pxx_m; CA.Pxx_s = Pxx_s; CA.Pyy_m = Pyy_m; CA.Pyy_s = Pyy_s;
    CA.x2 = x2; CA.y2 = y2; CA.hdr = hdr; CA.sched = sched;

    /* init: softmins at eps_list[0] with null potentials */
    TA.fba = nullptr; TA.gab = nullptr; TA.faa = nullptr; TA.gbb = nullptr;
    TA.t = 0; TA.mode = 0;
    hipLaunchKernelGGL(tile_kernel, dim3(NBLK), dim3(256), 0, stream, TA);
    CA.fba_old = nullptr; CA.gab_old = nullptr; CA.faa_old = nullptr; CA.gbb_old = nullptr;
    CA.fba = fba[0]; CA.gab = gab[0]; CA.faa = faa[0]; CA.gbb = gbb[0];
    CA.t = 0; CA.mode = 0;
    hipLaunchKernelGGL(comb_kernel, dim3(64), dim3(256), 0, stream, CA);

    /* annealing loop */
    int cur = 0;
    for (int t = 0; t < MAX_ITERS; t++) {
        int nx = cur ^ 1;
        TA.fba = fba[cur]; TA.gab = gab[cur]; TA.faa = faa[cur]; TA.gbb = gbb[cur];
        TA.t = t; TA.mode = 1;
        hipLaunchKernelGGL(tile_kernel, dim3(NBLK), dim3(256), 0, stream, TA);
        CA.fba_old = fba[cur]; CA.gab_old = gab[cur]; CA.faa_old = faa[cur]; CA.gbb_old = gbb[cur];
        CA.fba = fba[nx]; CA.gab = gab[nx]; CA.faa = faa[nx]; CA.gbb = gbb[nx];
        CA.t = t; CA.mode = 1;
        hipLaunchKernelGGL(comb_kernel, dim3(64), dim3(256), 0, stream, CA);
        cur = nx;
    }

    /* final extrapolation at eps_final (t=-1 -> last eps), no averaging */
    int nx = cur ^ 1;
    TA.fba = fba[cur]; TA.gab = gab[cur]; TA.faa = faa[cur]; TA.gbb = gbb[cur];
    TA.t = -1; TA.mode = 0;
    hipLaunchKernelGGL(tile_kernel, dim3(NBLK), dim3(256), 0, stream, TA);
    CA.fba_old = fba[cur]; CA.gab_old = gab[cur]; CA.faa_old = faa[cur]; CA.gbb_old = gbb[cur];
    CA.fba = fba[nx]; CA.gab = gab[nx]; CA.faa = faa[nx]; CA.gbb = gbb[nx];
    CA.t = -1; CA.mode = 0;
    hipLaunchKernelGGL(comb_kernel, dim3(64), dim3(256), 0, stream, CA);

    hipLaunchKernelGGL(reduce_kernel, dim3(1), dim3(256), 0, stream,
                       fba[nx], faa[nx], gab[nx], gbb[nx], out);
}

// Round 3
// 1156.968 us; speedup vs baseline: 3.4657x; 1.1171x over previous
//
#include <hip/hip_runtime.h>
#include <math.h>

#define NPTS 4096
#define DIM  64
#define MAX_ITERS 40
#define NCHUNK 32           /* 4096 / 128 */
#define TILE 128

#define ALOG (-8.317766166719343f)   /* -log(4096) */
#define L2E  (1.4426950408889634f)
#define LN2  (0.6931471805599453f)

#if __has_builtin(__builtin_amdgcn_exp2f)
#define EXP2F(x) __builtin_amdgcn_exp2f(x)
#else
#define EXP2F(x) exp2f(x)
#endif
#if __has_builtin(__builtin_amdgcn_logf)
#define LOG2F(x) __builtin_amdgcn_logf(x)
#else
#define LOG2F(x) log2f(x)
#endif

typedef _Float16 half8 __attribute__((ext_vector_type(8)));

/* ---------------- min/max partial reduction (per-dim, both x and y) ------ */
__global__ void minmax_part_kernel(const float* __restrict__ x,
                                   const float* __restrict__ y,
                                   float* __restrict__ partmn,
                                   float* __restrict__ partmx) {
    int t = threadIdx.x;
    int bid = blockIdx.x;               // 128 blocks
    int g0 = bid * 256 + t;
    const int total = NPTS * DIM;
    float mn = INFINITY, mx = -INFINITY;
    for (int g = g0; g < total; g += 128 * 256) {
        float v = x[g]; mn = fminf(mn, v); mx = fmaxf(mx, v);
        float w = y[g]; mn = fminf(mn, w); mx = fmaxf(mx, w);
    }
    __shared__ float smn[256], smx[256];
    smn[t] = mn; smx[t] = mx;
    __syncthreads();
    if (t < 64) {
        for (int q = 1; q < 4; q++) {
            mn = fminf(mn, smn[t + 64 * q]);
            mx = fmaxf(mx, smx[t + 64 * q]);
        }
        partmn[bid * 64 + t] = mn;
        partmx[bid * 64 + t] = mx;
    }
}

/* ---------------- eps schedule (replicates numpy in f64) ----------------- */
__global__ void schedule_kernel(const float* __restrict__ partmn,
                                const float* __restrict__ partmx,
                                int* __restrict__ hdr,
                                float* __restrict__ sched) {
    int d = threadIdx.x;  // 64 threads
    float mn = INFINITY, mx = -INFINITY;
    for (int b = 0; b < 128; b++) {
        mn = fminf(mn, partmn[b * 64 + d]);
        mx = fmaxf(mx, partmx[b * 64 + d]);
    }
    float range = mx - mn;
    __shared__ float r2[64];
    r2[d] = range * range;
    __syncthreads();
    if (d == 0) {
        float ss = 0.f;
        for (int k = 0; k < 64; k++) ss += r2[k];
        float diam_f = sqrtf(ss);
        double diam = (double)diam_f;
        double start = 2.0 * log(diam);
        double stop  = 2.0 * log(0.05);
        double step  = 2.0 * log(0.8);
        int n_ar = (int)ceil((stop - start) / step);
        if (n_ar < 0) n_ar = 0;
        int n_eps = n_ar + 2;
        if (n_eps > 64) n_eps = 64;
        sched[0] = (float)(diam * diam);
        for (int k = 0; k < n_ar && (1 + k) < 63; k++)
            sched[1 + k] = (float)exp(start + step * (double)k);
        sched[n_eps - 1] = 0.0025f;
        for (int k = n_eps; k < 64; k++) sched[k] = 0.0025f;
        hdr[0] = n_eps;
    }
}

/* ---------------- squared norms (wave per row) --------------------------- */
__global__ void sqnorm_kernel(const float* __restrict__ X, float* __restrict__ out) {
    int wave = (blockIdx.x * blockDim.x + threadIdx.x) >> 6;
    int lane = threadIdx.x & 63;
    if (wave >= NPTS) return;
    float v = X[wave * DIM + lane];
    float s = v * v;
    for (int o = 32; o > 0; o >>= 1) s += __shfl_xor(s, o, 64);
    if (lane == 0) out[wave] = s;
}

/* ---------------- Gram: G[i][j] = dot(A_i, B_j) -> f16, 64x64 tile ------- */
__global__ __launch_bounds__(256) void gram_kernel(const float* __restrict__ A,
                                                   const float* __restrict__ B,
                                                   _Float16* __restrict__ G) {
    __shared__ float As[64][68], Bs[64][68];
    int t = threadIdx.x;
    int i0 = blockIdx.y * 64, j0 = blockIdx.x * 64;
    for (int q = 0; q < 4; q++) {
        int fi = q * 256 + t;
        int r = fi >> 4, c4 = (fi & 15) * 4;
        *(float4*)&As[r][c4] = *(const float4*)&A[(i0 + r) * DIM + c4];
        *(float4*)&Bs[r][c4] = *(const float4*)&B[(j0 + r) * DIM + c4];
    }
    __syncthreads();
    int tx = t & 15, ty = t >> 4;
    float acc[4][4] = {};
    for (int k = 0; k < 64; k++) {
        float a[4], b[4];
#pragma unroll
        for (int u = 0; u < 4; u++) a[u] = As[ty + 16 * u][k];
#pragma unroll
        for (int v = 0; v < 4; v++) b[v] = Bs[tx + 16 * v][k];
#pragma unroll
        for (int u = 0; u < 4; u++)
#pragma unroll
            for (int v = 0; v < 4; v++) acc[u][v] = fmaf(a[u], b[v], acc[u][v]);
    }
    for (int u = 0; u < 4; u++)
        for (int v = 0; v < 4; v++)
            G[(size_t)(i0 + ty + 16 * u) * NPTS + j0 + tx + 16 * v] = (_Float16)acc[u][v];
}

/* ---------------- fused tile pass: all 3 matrices, both directions ------- */
struct TileArgs {
    const _Float16 *Gxy, *Gxx, *Gyy;
    const float *x2, *y2;
    const float *fba, *gab, *faa, *gbb;      /* prev potentials (null=init) */
    float *PxyR_m, *PxyR_s, *PxyC_m, *PxyC_s;
    float *Pxx_m, *Pxx_s, *Pyy_m, *Pyy_s;
    const int* hdr; const float* sched;
    int t; int mode;                          /* mode1=anneal iter, mode0=init/final */
};

__global__ __launch_bounds__(256) void tile_kernel(TileArgs A) {
    int n_eps = A.hdr[0];
    if (A.mode == 1 && A.t >= n_eps) return;  /* padded iteration */
    int idx = (A.t < 0) ? (n_eps - 1) : A.t;
    float eps = A.sched[idx];
    float inv2 = (1.0f / eps) * L2E;

    int b = blockIdx.x;
    const _Float16 *G;
    const float *hc_f, *hc_sq, *hr_f, *hr_sq;
    float *Prm, *Prs, *Pcm, *Pcs;
    int ti, tj; bool diag = false;
    if (b < 1024) {
        ti = b >> 5; tj = b & 31;
        G = A.Gxy;
        hc_f = A.gab; hc_sq = A.y2;      /* row-dir h over columns j (y side) */
        hr_f = A.fba; hr_sq = A.x2;      /* col-dir h over rows i (x side)    */
        Prm = A.PxyR_m; Prs = A.PxyR_s; Pcm = A.PxyC_m; Pcs = A.PxyC_s;
    } else {
        int u;
        if (b < 1024 + 528) {
            u = b - 1024; G = A.Gxx; hc_f = A.faa; hc_sq = A.x2;
            Prm = A.Pxx_m; Prs = A.Pxx_s; Pcm = A.Pxx_m; Pcs = A.Pxx_s;
        } else {
            u = b - 1552; G = A.Gyy; hc_f = A.gbb; hc_sq = A.y2;
            Prm = A.Pyy_m; Prs = A.Pyy_s; Pcm = A.Pyy_m; Pcs = A.Pyy_s;
        }
        hr_f = hc_f; hr_sq = hc_sq;
        ti = 0; while (u >= NCHUNK - ti) { u -= NCHUNK - ti; ti++; }
        tj = ti + u;
        diag = (ti == tj);
    }
    const float base2 = ALOG * L2E;

    __shared__ float tile[64][65];
    __shared__ float h2c[128], h2r[128];
    __shared__ float red_m[4][64], red_s[4][64];

    int tt = threadIdx.x;
    int gi0 = ti * TILE, gj0 = tj * TILE;
    if (tt < 128) {
        int j = gj0 + tt;
        float f = hc_f ? hc_f[j] : 0.f;
        h2c[tt] = base2 + (f - 0.5f * hc_sq[j]) * inv2;
    } else {
        int i = gi0 + (tt - 128);
        float f = hr_f ? hr_f[i] : 0.f;
        h2r[tt - 128] = base2 + (f - 0.5f * hr_sq[i]) * inv2;
    }

    float rm[2] = {-INFINITY, -INFINITY}, rs[2] = {0.f, 0.f};
    float cm[2] = {-INFINITY, -INFINITY}, cs[2] = {0.f, 0.f};
    int lr = tt & 63, lq = tt >> 6;

    for (int qc = 0; qc < 2; qc++) {
        for (int qr = 0; qr < 2; qr++) {
            __syncthreads();
            {   /* stage 64x64 f16 quadrant -> f32 LDS */
                const _Float16* src = G + (size_t)(gi0 + qr * 64) * NPTS + gj0 + qc * 64;
                for (int q = 0; q < 2; q++) {
                    int fi = q * 256 + tt;
                    int r = fi >> 3, c8 = (fi & 7) * 8;
                    half8 h = *(const half8*)(src + (size_t)r * NPTS + c8);
#pragma unroll
                    for (int j = 0; j < 8; j++) tile[r][c8 + j] = (float)h[j];
                }
            }
            __syncthreads();
            {   /* row-dir: thread owns row lr (slab qr), col quarter lq */
                float v[16], lm = -INFINITY;
#pragma unroll
                for (int k = 0; k < 16; k++) {
                    v[k] = fmaf(tile[lr][lq * 16 + k], inv2, h2c[qc * 64 + lq * 16 + k]);
                    lm = fmaxf(lm, v[k]);
                }
                float nm = fmaxf(rm[qr], lm);
                float acc = rs[qr] * EXP2F(rm[qr] - nm);
#pragma unroll
                for (int k = 0; k < 16; k++) acc += EXP2F(v[k] - nm);
                rm[qr] = nm; rs[qr] = acc;
            }
            if (!diag) {   /* col-dir: thread owns col lr (slab qc), row quarter lq */
                float v[16], lm = -INFINITY;
#pragma unroll
                for (int k = 0; k < 16; k++) {
                    v[k] = fmaf(tile[lq * 16 + k][lr], inv2, h2r[qr * 64 + lq * 16 + k]);
                    lm = fmaxf(lm, v[k]);
                }
                float nm = fmaxf(cm[qc], lm);
                float acc = cs[qc] * EXP2F(cm[qc] - nm);
#pragma unroll
                for (int k = 0; k < 16; k++) acc += EXP2F(v[k] - nm);
                cm[qc] = nm; cs[qc] = acc;
            }
        }
    }

    /* flush row partials: P[tj][gi] */
    for (int qr = 0; qr < 2; qr++) {
        __syncthreads();
        red_m[lq][lr] = rm[qr]; red_s[lq][lr] = rs[qr];
        __syncthreads();
        if (tt < 64) {
            float M = fmaxf(fmaxf(red_m[0][tt], red_m[1][tt]),
                            fmaxf(red_m[2][tt], red_m[3][tt]));
            float S = red_s[0][tt] * EXP2F(red_m[0][tt] - M)
                    + red_s[1][tt] * EXP2F(red_m[1][tt] - M)
                    + red_s[2][tt] * EXP2F(red_m[2][tt] - M)
                    + red_s[3][tt] * EXP2F(red_m[3][tt] - M);
            int gi = gi0 + qr * 64 + tt;
            Prm[tj * NPTS + gi] = M; Prs[tj * NPTS + gi] = S;
        }
    }
    /* flush col partials: P[ti][gj] */
    if (!diag) {
        for (int qc = 0; qc < 2; qc++) {
            __syncthreads();
            red_m[lq][lr] = cm[qc]; red_s[lq][lr] = cs[qc];
            __syncthreads();
            if (tt < 64) {
                float M = fmaxf(fmaxf(red_m[0][tt], red_m[1][tt]),
                                fmaxf(red_m[2][tt], red_m[3][tt]));
                float S = red_s[0][tt] * EXP2F(red_m[0][tt] - M)
                        + red_s[1][tt] * EXP2F(red_m[1][tt] - M)
                        + red_s[2][tt] * EXP2F(red_m[2][tt] - M)
                        + red_s[3][tt] * EXP2F(red_m[3][tt] - M);
                int gj = gj0 + qc * 64 + tt;
                Pcm[ti * NPTS + gj] = M; Pcs[ti * NPTS + gj] = S;
            }
        }
    }
}

/* ---------------- combine: merge 32 chunk partials per output row -------- */
struct CombArgs {
    const float *PxyR_m, *PxyR_s, *PxyC_m, *PxyC_s;
    const float *Pxx_m, *Pxx_s, *Pyy_m, *Pyy_s;
    const float *x2, *y2;
    const float *fba_old, *gab_old, *faa_old, *gbb_old;
    float *fba, *gab, *faa, *gbb;
    const int* hdr; const float* sched; int t; int mode;
};

__global__ void comb_kernel(CombArgs A) {
    int vec = blockIdx.x >> 4;                       /* 16 blocks per vector */
    int r = (blockIdx.x & 15) * 256 + threadIdx.x;
    int n_eps = A.hdr[0];
    const float *Pm, *Ps, *sq, *old; float *out;
    switch (vec) {
        case 0:  Pm = A.PxyR_m; Ps = A.PxyR_s; sq = A.x2; old = A.fba_old; out = A.fba; break;
        case 1:  Pm = A.PxyC_m; Ps = A.PxyC_s; sq = A.y2; old = A.gab_old; out = A.gab; break;
        case 2:  Pm = A.Pxx_m;  Ps = A.Pxx_s;  sq = A.x2; old = A.faa_old; out = A.faa; break;
        default: Pm = A.Pyy_m;  Ps = A.Pyy_s;  sq = A.y2; old = A.gbb_old; out = A.gbb; break;
    }
    if (A.mode == 1 && A.t >= n_eps) { out[r] = old[r]; return; }
    int idx = (A.t < 0) ? (n_eps - 1) : A.t;
    float eps = A.sched[idx];
    float M = -INFINITY;
    for (int q = 0; q < NCHUNK; q++) M = fmaxf(M, Pm[q * NPTS + r]);
    float S = 0.f;
    for (int q = 0; q < NCHUNK; q++) S += Ps[q * NPTS + r] * EXP2F(Pm[q * NPTS + r] - M);
    float res = 0.5f * sq[r] - eps * LN2 * (M + LOG2F(S));
    out[r] = (A.mode == 1) ? 0.5f * (old[r] + res) : res;
}

/* ---------------- final reduction: mean(fba-faa)+mean(gab-gbb) ----------- */
__global__ void reduce_kernel(const float* __restrict__ fba, const float* __restrict__ faa,
                              const float* __restrict__ gab, const float* __restrict__ gbb,
                              float* __restrict__ out) {
    int t = threadIdx.x;
    double s1 = 0.0, s2 = 0.0;
    for (int i = t; i < NPTS; i += 256) {
        s1 += (double)fba[i] - (double)faa[i];
        s2 += (double)gab[i] - (double)gbb[i];
    }
    __shared__ double sh1[256], sh2[256];
    sh1[t] = s1; sh2[t] = s2;
    __syncthreads();
    for (int o = 128; o > 0; o >>= 1) {
        if (t < o) { sh1[t] += sh1[t + o]; sh2[t] += sh2[t + o]; }
        __syncthreads();
    }
    if (t == 0) out[0] = (float)(sh1[0] / NPTS + sh2[0] / NPTS);
}

extern "C" void kernel_launch(void* const* d_in, const int* in_sizes, int n_in,
                              void* d_out, int out_size, void* d_ws, size_t ws_size,
                              hipStream_t stream) {
    const float* x = (const float*)d_in[0];
    const float* y = (const float*)d_in[1];
    float* out = (float*)d_out;
    float* w = (float*)d_ws;

    int*   hdr   = (int*)w;                /* 16 */
    float* sched = w + 16;                 /* 64 */
    float* pmn   = w + 80;                 /* 8192 */
    float* pmx   = w + 8272;               /* 8192 */
    float* x2    = w + 16464;              /* 4096 */
    float* y2    = w + 20560;              /* 4096 */
    float* st    = w + 24656;              /* 8*4096 ping-pong state */
    float* fba[2] = { st,            st + 4096 };
    float* gab[2] = { st + 2*4096,   st + 3*4096 };
    float* faa[2] = { st + 4*4096,   st + 5*4096 };
    float* gbb[2] = { st + 6*4096,   st + 7*4096 };
    float* P = w + 57424;                  /* 8 x 131072 partials */
    float* PxyR_m = P;             float* PxyR_s = P + 131072;
    float* PxyC_m = P + 2*131072;  float* PxyC_s = P + 3*131072;
    float* Pxx_m  = P + 4*131072;  float* Pxx_s  = P + 5*131072;
    float* Pyy_m  = P + 6*131072;  float* Pyy_s  = P + 7*131072;
    const size_t NN = (size_t)NPTS * NPTS;
    _Float16* Gxy = (_Float16*)(w + 2097152);
    _Float16* Gxx = Gxy + NN;
    _Float16* Gyy = Gxx + NN;

    /* setup */
    hipLaunchKernelGGL(minmax_part_kernel, dim3(128), dim3(256), 0, stream, x, y, pmn, pmx);
    hipLaunchKernelGGL(schedule_kernel, dim3(1), dim3(64), 0, stream, pmn, pmx, hdr, sched);
    hipLaunchKernelGGL(sqnorm_kernel, dim3(1024), dim3(256), 0, stream, x, x2);
    hipLaunchKernelGGL(sqnorm_kernel, dim3(1024), dim3(256), 0, stream, y, y2);
    hipLaunchKernelGGL(gram_kernel, dim3(64, 64), dim3(256), 0, stream, x, y, Gxy);
    hipLaunchKernelGGL(gram_kernel, dim3(64, 64), dim3(256), 0, stream, x, x, Gxx);
    hipLaunchKernelGGL(gram_kernel, dim3(64, 64), dim3(256), 0, stream, y, y, Gyy);

    const int NBLK = 1024 + 528 + 528;     /* 2080 */
    TileArgs TA;
    TA.Gxy = Gxy; TA.Gxx = Gxx; TA.Gyy = Gyy;
    TA.x2 = x2; TA.y2 = y2;
    TA.PxyR_m = PxyR_m; TA.PxyR_s = PxyR_s; TA.PxyC_m = PxyC_m; TA.PxyC_s = PxyC_s;
    TA.Pxx_m = Pxx_m; TA.Pxx_s = Pxx_s; TA.Pyy_m = Pyy_m; TA.Pyy_s = Pyy_s;
    TA.hdr = hdr; TA.sched = sched;

    CombArgs CA;
    CA.PxyR_m = PxyR_m; CA.PxyR_s = PxyR_s; CA.PxyC_m = PxyC_m; CA.PxyC_s = PxyC_s;
    CA.Pxx_m = Pxx_m; CA.Pxx_s = Pxx_s; CA.Pyy_m = Pyy_m; CA.Pyy_s = Pyy_s;
    CA.x2 = x2; CA.y2 = y2; CA.hdr = hdr; CA.sched = sched;

    /* init: softmins at eps_list[0] with null potentials */
    TA.fba = nullptr; TA.gab = nullptr; TA.faa = nullptr; TA.gbb = nullptr;
    TA.t = 0; TA.mode = 0;
    hipLaunchKernelGGL(tile_kernel, dim3(NBLK), dim3(256), 0, stream, TA);
    CA.fba_old = nullptr; CA.gab_old = nullptr; CA.faa_old = nullptr; CA.gbb_old = nullptr;
    CA.fba = fba[0]; CA.gab = gab[0]; CA.faa = faa[0]; CA.gbb = gbb[0];
    CA.t = 0; CA.mode = 0;
    hipLaunchKernelGGL(comb_kernel, dim3(64), dim3(256), 0, stream, CA);

    /* annealing loop */
    int cur = 0;
    for (int t = 0; t < MAX_ITERS; t++) {
        int nx = cur ^ 1;
        TA.fba = fba[cur]; TA.gab = gab[cur]; TA.faa = faa[cur]; TA.gbb = gbb[cur];
        TA.t = t; TA.mode = 1;
        hipLaunchKernelGGL(tile_kernel, dim3(NBLK), dim3(256), 0, stream, TA);
        CA.fba_old = fba[cur]; CA.gab_old = gab[cur]; CA.faa_old = faa[cur]; CA.gbb_old = gbb[cur];
        CA.fba = fba[nx]; CA.gab = gab[nx]; CA.faa = faa[nx]; CA.gbb = gbb[nx];
        CA.t = t; CA.mode = 1;
        hipLaunchKernelGGL(comb_kernel, dim3(64), dim3(256), 0, stream, CA);
        cur = nx;
    }

    /* final extrapolation at eps_final (t=-1 -> last eps), no averaging */
    int nx = cur ^ 1;
    TA.fba = fba[cur]; TA.gab = gab[cur]; TA.faa = faa[cur]; TA.gbb = gbb[cur];
    TA.t = -1; TA.mode = 0;
    hipLaunchKernelGGL(tile_kernel, dim3(NBLK), dim3(256), 0, stream, TA);
    CA.fba_old = fba[cur]; CA.gab_old = gab[cur]; CA.faa_old = faa[cur]; CA.gbb_old = gbb[cur];
    CA.fba = fba[nx]; CA.gab = gab[nx]; CA.faa = faa[nx]; CA.gbb = gbb[nx];
    CA.t = -1; CA.mode = 0;
    hipLaunchKernelGGL(comb_kernel, dim3(64), dim3(256), 0, stream, CA);

    hipLaunchKernelGGL(reduce_kernel, dim3(1), dim3(256), 0, stream,
                       fba[nx], faa[nx], gab[nx], gbb[nx], out);
}